// Round 1
// baseline (618.144 us; speedup 1.0000x reference)
//
#include <hip/hip_runtime.h>

// GlobalFilter: y = irfft(rfft(x, n=10) * w, n=10)  ==  per-(b,d) circular conv of
// x[b,d,:] (len 10) with kernel t_d derived from the complex weight w_d[6].
//
//   t_d[j] = 0.1*( Re w0 + (-1)^j Re w5
//                  + 2*sum_{k=1..4} ( Re wk * cos(2*pi*k*j/10) - Im wk * sin(2*pi*k*j/10) ) )
//   y[n]   = sum_m x[m] * t_d[(n-m) mod 10]
//
// B=8192, DIM=1024, N=10. Memory-bound: 336 MB in + 336 MB out.
// One thread handles 2 consecutive rows (80 B -> 16B-aligned float4 traffic).

#define BB   8192
#define DIMM 1024
#define NW   10

__global__ __launch_bounds__(256) void GlobalFilter_45784351375638_kernel(
    const float* __restrict__ x,
    const float* __restrict__ w,
    float* __restrict__ y)
{
    // cos/sin(2*pi*p/10), p = 0..9 (compile-time folded after full unroll)
    const float c10[10] = {
        1.0f,  0.8090169943749474f,  0.30901699437494745f, -0.30901699437494745f,
        -0.8090169943749474f, -1.0f, -0.8090169943749474f, -0.30901699437494745f,
        0.30901699437494745f,  0.8090169943749474f };
    const float s10[10] = {
        0.0f,  0.5877852522924731f,  0.9510565162951535f,  0.9510565162951535f,
        0.5877852522924731f,  0.0f, -0.5877852522924731f, -0.9510565162951535f,
        -0.9510565162951535f, -0.5877852522924731f };

    const int tid = blockIdx.x * blockDim.x + threadIdx.x;   // handles rows 2*tid, 2*tid+1
    const int r0  = tid * 2;                                 // even; fits in int (max 8.4M)
    const int d0  = r0 & (DIMM - 1);                         // r0 even -> d0 even, d0+1 no wrap

    // ---- load 2 rows of x: 20 floats, 16B-aligned (80B per thread) ----
    const float4* xp = (const float4*)(x + (size_t)r0 * NW);
    float4 v0 = xp[0], v1 = xp[1], v2 = xp[2], v3 = xp[3], v4 = xp[4];
    float xr[2][NW] = {
        { v0.x, v0.y, v0.z, v0.w, v1.x, v1.y, v1.z, v1.w, v2.x, v2.y },
        { v2.z, v2.w, v3.x, v3.y, v3.z, v3.w, v4.x, v4.y, v4.z, v4.w } };

    // ---- load weights for d0, d0+1: 24 contiguous floats, 16B-aligned ----
    const float4* wp = (const float4*)(w + (size_t)d0 * 12);
    float4 w0 = wp[0], w1 = wp[1], w2 = wp[2], w3 = wp[3], w4 = wp[4], w5 = wp[5];
    float wf[24] = { w0.x,w0.y,w0.z,w0.w, w1.x,w1.y,w1.z,w1.w, w2.x,w2.y,w2.z,w2.w,
                     w3.x,w3.y,w3.z,w3.w, w4.x,w4.y,w4.z,w4.w, w5.x,w5.y,w5.z,w5.w };

    // ---- build the two circular-conv kernels t[2][10] ----
    float tt[2][NW];
#pragma unroll
    for (int rr = 0; rr < 2; ++rr) {
        const float* wd = &wf[rr * 12];          // [A0,B0, A1,B1, ..., A5,B5]
#pragma unroll
        for (int j = 0; j < NW; ++j) {
            float acc = wd[0] + ((j & 1) ? -wd[10] : wd[10]);   // Re w0 + (-1)^j Re w5
#pragma unroll
            for (int k = 1; k <= 4; ++k) {
                const int p = (k * j) % 10;                     // compile-time constant
                acc += 2.0f * (wd[2 * k] * c10[p] - wd[2 * k + 1] * s10[p]);
            }
            tt[rr][j] = 0.1f * acc;
        }
    }

    // ---- circular convolution: y[n] = sum_m x[m] * t[(n-m) mod 10] ----
    float out[2][NW];
#pragma unroll
    for (int rr = 0; rr < 2; ++rr) {
#pragma unroll
        for (int n = 0; n < NW; ++n) {
            float acc = 0.0f;
#pragma unroll
            for (int m = 0; m < NW; ++m) {
                acc += xr[rr][m] * tt[rr][(n - m + NW) % NW];   // index is compile-time
            }
            out[rr][n] = acc;
        }
    }

    // ---- store 2 rows: 5 float4 ----
    float4* yp = (float4*)(y + (size_t)r0 * NW);
    yp[0] = make_float4(out[0][0], out[0][1], out[0][2], out[0][3]);
    yp[1] = make_float4(out[0][4], out[0][5], out[0][6], out[0][7]);
    yp[2] = make_float4(out[0][8], out[0][9], out[1][0], out[1][1]);
    yp[3] = make_float4(out[1][2], out[1][3], out[1][4], out[1][5]);
    yp[4] = make_float4(out[1][6], out[1][7], out[1][8], out[1][9]);
}

extern "C" void kernel_launch(void* const* d_in, const int* in_sizes, int n_in,
                              void* d_out, int out_size, void* d_ws, size_t ws_size,
                              hipStream_t stream) {
    const float* x = (const float*)d_in[0];          // [8192, 1024, 10] fp32
    const float* w = (const float*)d_in[1];          // [1024, 6, 2] fp32
    float* y = (float*)d_out;                        // [8192, 1024, 10] fp32

    const int total_rows = BB * DIMM;                // 8,388,608
    const int threads    = total_rows / 2;           // 4,194,304
    const int block      = 256;
    const int grid       = threads / block;          // 16,384

    GlobalFilter_45784351375638_kernel<<<grid, block, 0, stream>>>(x, w, y);
}

// Round 2
// 534.463 us; speedup vs baseline: 1.1566x; 1.1566x over previous
//
#include <hip/hip_runtime.h>

// GlobalFilter: y = irfft(rfft(x, n=10) * w, n=10)  ==  per-(b,d) circular conv of
// x[b,d,:] (len 10) with kernel t_d derived from complex weight w_d[6]:
//
//   t_d[j] = 0.1*( Re w0 + (-1)^j Re w5
//                  + 2*sum_{k=1..4} ( Re wk * cos(2*pi*k*j/10) - Im wk * sin(2*pi*k*j/10) ) )
//   y[n]   = sum_m x[m] * t_d[(n-m) mod 10]
//
// B=8192, DIM=1024, N=10; 336 MB in + 336 MB out -> memory-bound, floor ~107 us.
// Round-1 lesson: 80B-strided per-lane float4 access = ~5x transaction amplification
// (2.46 TB/s, WRITE 419 MB vs 336 ideal). This version stages through a transposed
// LDS buffer so every global load/store is lane-contiguous float4.

#define BB   8192
#define DIMM 1024
#define NW   10
#define BLOCK 256
#define FPT  20                    // floats per thread (2 rows)
#define BLOCK_F4 (BLOCK * FPT / 4) // 1280 float4 per block

__global__ __launch_bounds__(BLOCK) void GlobalFilter_45784351375638_kernel(
    const float* __restrict__ x,
    const float* __restrict__ w,
    float* __restrict__ y)
{
    // transposed staging: lds[pos][thread] ; addr = pos*256 + g -> bank = g % 32
    __shared__ float lds[FPT][BLOCK];          // 20 KB

    const float c10[10] = {
        1.0f,  0.8090169943749474f,  0.30901699437494745f, -0.30901699437494745f,
        -0.8090169943749474f, -1.0f, -0.8090169943749474f, -0.30901699437494745f,
        0.30901699437494745f,  0.8090169943749474f };
    const float s10[10] = {
        0.0f,  0.5877852522924731f,  0.9510565162951535f,  0.9510565162951535f,
        0.5877852522924731f,  0.0f, -0.5877852522924731f, -0.9510565162951535f,
        -0.9510565162951535f, -0.5877852522924731f };

    const int t = threadIdx.x;
    const size_t base_f4 = (size_t)blockIdx.x * BLOCK_F4;

    // ---- phase 1: fully-coalesced global loads -> transposed LDS ----
    const float4* xg = (const float4*)x + base_f4;
    float4 v[5];
#pragma unroll
    for (int k = 0; k < 5; ++k) v[k] = xg[t + k * BLOCK];
#pragma unroll
    for (int k = 0; k < 5; ++k) {
        const int f = 4 * (t + k * BLOCK);     // block-local float index
        lds[(f    ) % FPT][(f    ) / FPT] = v[k].x;
        lds[(f + 1) % FPT][(f + 1) / FPT] = v[k].y;
        lds[(f + 2) % FPT][(f + 2) / FPT] = v[k].z;
        lds[(f + 3) % FPT][(f + 3) / FPT] = v[k].w;
    }
    __syncthreads();

    // ---- gather this thread's 2 rows (conflict-free: bank = t % 32, 2-way) ----
    float xr[2][NW];
#pragma unroll
    for (int j = 0; j < FPT; ++j) xr[j / NW][j % NW] = lds[j][t];

    // ---- weights for rows 2t, 2t+1 of this block ----
    const int r0 = (int)(((size_t)blockIdx.x * BLOCK + t) * 2);  // global row (even)
    const int d0 = r0 & (DIMM - 1);                              // even -> d0+1 no wrap
    const float4* wp = (const float4*)(w + (size_t)d0 * 12);
    float4 w0 = wp[0], w1 = wp[1], w2 = wp[2], w3 = wp[3], w4 = wp[4], w5 = wp[5];
    float wf[24] = { w0.x,w0.y,w0.z,w0.w, w1.x,w1.y,w1.z,w1.w, w2.x,w2.y,w2.z,w2.w,
                     w3.x,w3.y,w3.z,w3.w, w4.x,w4.y,w4.z,w4.w, w5.x,w5.y,w5.z,w5.w };

    // ---- build the two circular-conv kernels t[2][10] ----
    float tt[2][NW];
#pragma unroll
    for (int rr = 0; rr < 2; ++rr) {
        const float* wd = &wf[rr * 12];        // [A0,B0, A1,B1, ..., A5,B5]
#pragma unroll
        for (int j = 0; j < NW; ++j) {
            float acc = wd[0] + ((j & 1) ? -wd[10] : wd[10]);   // Re w0 + (-1)^j Re w5
#pragma unroll
            for (int k = 1; k <= 4; ++k) {
                const int p = (k * j) % 10;                     // compile-time constant
                acc += 2.0f * (wd[2 * k] * c10[p] - wd[2 * k + 1] * s10[p]);
            }
            tt[rr][j] = 0.1f * acc;
        }
    }

    // ---- circular convolution ----
    float out[2][NW];
#pragma unroll
    for (int rr = 0; rr < 2; ++rr) {
#pragma unroll
        for (int n = 0; n < NW; ++n) {
            float acc = 0.0f;
#pragma unroll
            for (int m = 0; m < NW; ++m) {
                acc += xr[rr][m] * tt[rr][(n - m + NW) % NW];   // compile-time index
            }
            out[rr][n] = acc;
        }
    }

    // ---- phase 2: transposed LDS -> fully-coalesced global stores ----
    __syncthreads();                            // done reading x from lds
#pragma unroll
    for (int j = 0; j < FPT; ++j) lds[j][t] = out[j / NW][j % NW];
    __syncthreads();

    float4* yg = (float4*)y + base_f4;
#pragma unroll
    for (int k = 0; k < 5; ++k) {
        const int f = 4 * (t + k * BLOCK);
        float4 o4;
        o4.x = lds[(f    ) % FPT][(f    ) / FPT];
        o4.y = lds[(f + 1) % FPT][(f + 1) / FPT];
        o4.z = lds[(f + 2) % FPT][(f + 2) / FPT];
        o4.w = lds[(f + 3) % FPT][(f + 3) / FPT];
        yg[t + k * BLOCK] = o4;
    }
}

extern "C" void kernel_launch(void* const* d_in, const int* in_sizes, int n_in,
                              void* d_out, int out_size, void* d_ws, size_t ws_size,
                              hipStream_t stream) {
    const float* x = (const float*)d_in[0];          // [8192, 1024, 10] fp32
    const float* w = (const float*)d_in[1];          // [1024, 6, 2] fp32
    float* y = (float*)d_out;                        // [8192, 1024, 10] fp32

    const int total_f4 = BB * DIMM * NW / 4;         // 20,971,520
    const int grid     = total_f4 / BLOCK_F4;        // 16,384

    GlobalFilter_45784351375638_kernel<<<grid, BLOCK, 0, stream>>>(x, w, y);
}